// Round 8
// baseline (148.462 us; speedup 1.0000x reference)
//
#include <hip/hip_runtime.h>
#include <hip/hip_bf16.h>
#include <cstdint>
#include <cstddef>

#define NN 1024
#define FF 256

typedef __attribute__((ext_vector_type(8))) short bf16x8;
typedef __attribute__((ext_vector_type(4))) float f32x4;

typedef __attribute__((address_space(1))) const void* gas_ptr;
typedef __attribute__((address_space(3))) void* las_ptr;

__device__ __forceinline__ short f2bf(float x) {
  unsigned int u = __float_as_uint(x);
  u = (u + 0x7fffu + ((u >> 16) & 1u)) >> 16;   // RNE
  return (short)u;
}

// ---- PT tiled layout (all bf16 matrices) ----
// 16-row x 32-k tiles (512 elems): elem(row,k) = ((k&31)>>3)*128 + (row&15)*8 + (k&7)
// A wave load at (tile_base + lane*8) IS the MFMA fragment:
//   lane -> (row = lane&15, k = (lane>>4)*8 + j)
// Ahat (1024x1024/bw): bw<<20 + (r>>4)<<14 + (k>>5)<<9 + pt(r,k)
// G    (F x 1024/bw) : bw*F*1024 + (f>>4)<<14 + (n>>5)<<9 + pt(f,n)
// WT   (F_OUT x 256) : (fo>>4)*4096 + (fi>>5)<<9 + pt(fo,fi)

// ---- fused: d = rsqrt(rowsum(adj)+1), Ahat = (adj+I) bf16 PT-tiled ---------
__global__ __launch_bounds__(256)
void dinv_cast(const float* __restrict__ adj, float* __restrict__ dinv,
               short* __restrict__ Ahat) {
  __shared__ float wsum[64];
  int b = blockIdx.x;                          // 0..2047 = bw*64 + stripe
  int bw = b >> 6, s = b & 63;
  int t = threadIdx.x;
  int wid = t >> 6, lane = t & 63;
  int row = lane & 15;                         // local row in stripe
  int rloc = (s << 4) + row;                   // row in matrix
  int kg = (lane >> 4) & 3;
  const float* arow = adj + ((size_t)(bw << 10) + rloc) * NN;
  short* outb = Ahat + ((size_t)bw << 20) + ((size_t)s << 14) + (t << 3);
  float ssum = 0.f;
  #pragma unroll
  for (int it = 0; it < 8; it++) {
    int col = (it << 7) + (wid << 5) + (kg << 3);
    float4 a0 = *(const float4*)(arow + col);
    float4 a1 = *(const float4*)(arow + col + 4);
    float v[8] = {a0.x, a0.y, a0.z, a0.w, a1.x, a1.y, a1.z, a1.w};
    union { ushort o[8]; int4 q; } pk;
    #pragma unroll
    for (int j = 0; j < 8; j++) {
      v[j] += (rloc == col + j) ? 1.f : 0.f;
      ssum += v[j];
      pk.o[j] = (ushort)f2bf(v[j]);
    }
    *(int4*)(outb + (it << 11)) = pk.q;
  }
  ssum += __shfl_down(ssum, 32, 64);
  ssum += __shfl_down(ssum, 16, 64);
  if (lane < 16) wsum[(wid << 4) + lane] = ssum;
  __syncthreads();
  if (t < 16) {
    float tot = wsum[t] + wsum[16 + t] + wsum[32 + t] + wsum[48 + t];
    dinv[(bw << 10) + (s << 4) + t] = rsqrtf(tot);
  }
}

// ---- X [bw][n][256] fp32 -> G1 = d[n]*X, PT(f, n) bf16 ---------------------
__global__ __launch_bounds__(256)
void transpose_x(const float* __restrict__ X, const float* __restrict__ dinv,
                 short* __restrict__ XT) {
  __shared__ short T[64][72];
  int bwo = blockIdx.z;
  int n0 = blockIdx.x << 6, f0 = blockIdx.y << 6;
  int t = threadIdx.x;
  {
    int n = t >> 2, fc = (t & 3) << 4;
    float dn = dinv[(bwo << 10) + n0 + n];
    const float* src = X + (((size_t)bwo * NN + n0 + n) * FF) + f0 + fc;
    #pragma unroll
    for (int i = 0; i < 4; i++) {
      float4 v = ((const float4*)src)[i];
      ushort4 p;
      p.x = (unsigned short)f2bf(v.x * dn); p.y = (unsigned short)f2bf(v.y * dn);
      p.z = (unsigned short)f2bf(v.z * dn); p.w = (unsigned short)f2bf(v.w * dn);
      *(ushort4*)&T[n][fc + (i << 2)] = p;
    }
  }
  __syncthreads();
  {
    int f = t >> 2, nc = (t & 3) << 4;
    int fg = f0 + f, ng = n0 + nc;
    short tmp[16];
    #pragma unroll
    for (int i = 0; i < 16; i++) tmp[i] = T[nc + i][f];
    size_t e0 = ((size_t)bwo << 18) + ((size_t)(fg >> 4) << 14) + ((ng >> 5) << 9)
              + (((ng & 31) >> 3) << 7) + ((fg & 15) << 3);
    *(int4*)(XT + e0)       = *(int4*)&tmp[0];
    *(int4*)(XT + e0 + 128) = *(int4*)&tmp[8];
  }
}

// ---- W [256][FO] fp32 -> WT PT(fo, fi) bf16 --------------------------------
__global__ __launch_bounds__(256)
void transpose_w(const float* __restrict__ W, short* __restrict__ WT, int FO) {
  int idx = blockIdx.x * 256 + threadIdx.x;
  if (idx >= FO * 256) return;
  int fo = idx >> 8, fi = idx & 255;
  size_t e = (size_t)((fo >> 4) << 12) + ((fi >> 5) << 9)
           + (((fi & 31) >> 3) << 7) + ((fo & 15) << 3) + (fi & 7);
  WT[e] = f2bf(W[fi * FO + fo]);
}

// ---------------- fused layer ----------------------------------------------
// Grid 256 (8 XCD x 4 bw x 8 rb), 512 thr (8 waves = 2wr x 4wf), 1 block/CU.
// Block tile: 128 r x 256 f; wave 64 r x 64 f. A-tile (128x64) LDS-staged,
// double-buffered via global_load_lds (PT layout = linear, conflict-free
// ds_reads); ONE s_barrier per K64 with counted vmcnt(8) (next stage stays
// in flight). H register-direct (x2 dup hits L1 under lockstep).
template<int F_OUT, bool FINAL>
__global__ __launch_bounds__(512, 2)
void gcn_layer(const short* __restrict__ Ahat,    // PT tiled (A+I) bf16
               const float* __restrict__ dinv,
               const short* __restrict__ Gin,     // PT tiled g = d*h, F=256
               const short* __restrict__ WT,      // PT tiled
               const float* __restrict__ bias,
               short* __restrict__ Gout,          // PT tiled, F_OUT
               float* __restrict__ Out) {         // [32][1024][F_OUT] fp32
  __shared__ short lds[34816];                    // A dbuf 2x16KB; aggL[128][272]

  int b = blockIdx.x;
  int x = b & 7, m = b >> 3;
  int bw = (x << 2) + (m >> 3);                   // same-XCD neighbors share bw
  int rb = m & 7;
  int r0 = rb << 7;                               // 128 rows / block

  int tid = threadIdx.x;
  int wid = tid >> 6, lane = tid & 63;
  int l15 = lane & 15, l4 = lane >> 4;            // l4 in 0..3
  int wr = wid >> 2, wf = wid & 3;

  const short* Hb = Gin + ((size_t)bw << 18) + ((size_t)(wf << 2) << 14) + (lane << 3);
  const float* dvB = dinv + (bw << 10);

  // stage A-tile rows r0..r0+127, k-tiles 2T,2T+1 -> buf sel (16KB, linear)
  auto stage = [&](int sel, int T) {
    const short* gb = Ahat + ((size_t)bw << 20) + ((size_t)(T << 1) << 9);
    short* dst = lds + (sel << 13);
    #pragma unroll
    for (int i = 0; i < 2; i++) {
      int slot = (i << 9) + tid;                 // 0..1023, 16B each
      int s = slot >> 7, c = slot & 127;         // stripe, 16B chunk in 2KB
      const short* g = gb + ((size_t)((rb << 3) + s) << 14) + (c << 3);
      __builtin_amdgcn_global_load_lds((gas_ptr)g, (las_ptr)(dst + (slot << 3)), 16, 0, 0);
    }
  };

  f32x4 acc[4][4];                                // [ah(f)][aa(r)]
  #pragma unroll
  for (int ah = 0; ah < 4; ah++)
    #pragma unroll
    for (int aa = 0; aa < 4; aa++) acc[ah][aa] = f32x4{0.f, 0.f, 0.f, 0.f};

  stage(0, 0);

  for (int t = 0; t < 16; ++t) {
    // H fragments for this K64 (register-direct from L2)
    bf16x8 h[4][2];
    #pragma unroll
    for (int fh = 0; fh < 4; fh++) {
      h[fh][0] = *(const bf16x8*)(Hb + ((size_t)fh << 14) + ((size_t)(2 * t) << 9));
      h[fh][1] = *(const bf16x8*)(Hb + ((size_t)fh << 14) + ((size_t)(2 * t + 1) << 9));
    }
    // drain current A-stage (oldest 2 in queue), keep H(8) in flight
    asm volatile("s_waitcnt vmcnt(8)" ::: "memory");
    __builtin_amdgcn_sched_barrier(0);
    __builtin_amdgcn_s_barrier();
    __builtin_amdgcn_sched_barrier(0);
    if (t < 15) stage((t + 1) & 1, t + 1);       // async, lands before next barrier
    const short* ab = lds + ((t & 1) << 13);
    bf16x8 a[4][2];
    #pragma unroll
    for (int aa = 0; aa < 4; aa++) {
      int sa = (wr << 2) + aa;
      a[aa][0] = *(const bf16x8*)(ab + (sa << 10) + (lane << 3));
      a[aa][1] = *(const bf16x8*)(ab + (sa << 10) + 512 + (lane << 3));
    }
    __builtin_amdgcn_s_setprio(1);
    #pragma unroll
    for (int kt = 0; kt < 2; kt++)
      #pragma unroll
      for (int ah = 0; ah < 4; ah++)
        #pragma unroll
        for (int aa = 0; aa < 4; aa++)
          acc[ah][aa] = __builtin_amdgcn_mfma_f32_16x16x32_bf16(
              h[ah][kt], a[aa][kt], acc[ah][aa], 0, 0, 0);
    __builtin_amdgcn_s_setprio(0);
  }

  // all waves done reading ABUF before aggL (overlaps it) is written
  __builtin_amdgcn_sched_barrier(0);
  __builtin_amdgcn_s_barrier();
  __builtin_amdgcn_sched_barrier(0);

  // ---- agg = d[r]*acc -> LDS bf16 [128][272], XOR-swizzled ----
  float dsc[4];
  #pragma unroll
  for (int aa = 0; aa < 4; aa++) dsc[aa] = dvB[r0 + (wr << 6) + (aa << 4) + l15];
  #pragma unroll
  for (int ah = 0; ah < 4; ah++)
    #pragma unroll
    for (int aa = 0; aa < 4; aa++) {
      int r = (wr << 6) + (aa << 4) + l15;
      int fB = ((wf << 6) + (ah << 4) + (l4 << 2)) << 1;   // byte col
      int off = (r * 544 + (fB ^ ((r & 7) << 4))) >> 1;
      ushort4 p;
      p.x = (unsigned short)f2bf(acc[ah][aa][0] * dsc[aa]);
      p.y = (unsigned short)f2bf(acc[ah][aa][1] * dsc[aa]);
      p.z = (unsigned short)f2bf(acc[ah][aa][2] * dsc[aa]);
      p.w = (unsigned short)f2bf(acc[ah][aa][3] * dsc[aa]);
      *(ushort4*)(lds + off) = p;
    }
  asm volatile("s_waitcnt lgkmcnt(0)" ::: "memory");
  __builtin_amdgcn_sched_barrier(0);
  __builtin_amdgcn_s_barrier();
  __builtin_amdgcn_sched_barrier(0);

  // ---- stage 2: out = relu(agg @ W + b), K = 256, W from L2 ----
  constexpr int NFO = F_OUT / 64;                 // fo-tiles per wave
  const short* Wbase = WT + (size_t)(wf * NFO) * 4096 + (lane << 3);
  f32x4 acc2[4][NFO];
  #pragma unroll
  for (int am = 0; am < 4; am++)
    #pragma unroll
    for (int nf = 0; nf < NFO; nf++) acc2[am][nf] = f32x4{0.f, 0.f, 0.f, 0.f};

  #pragma unroll
  for (int kt = 0; kt < 8; kt++) {
    bf16x8 af[4];
    #pragma unroll
    for (int am = 0; am < 4; am++) {
      int r = (wr << 6) + (am << 4) + l15;
      int fB = (kt << 6) + (l4 << 4);
      af[am] = *(const bf16x8*)(lds + ((r * 544 + (fB ^ ((r & 7) << 4))) >> 1));
    }
    #pragma unroll
    for (int nf = 0; nf < NFO; nf++) {
      bf16x8 wv = *(const bf16x8*)(Wbase + (size_t)nf * 4096 + (kt << 9));
      #pragma unroll
      for (int am = 0; am < 4; am++)
        acc2[am][nf] = __builtin_amdgcn_mfma_f32_16x16x32_bf16(af[am], wv, acc2[am][nf], 0, 0, 0);
    }
  }

  // ---- epilogue: bias + relu (+d[node] for g-form) + store ----
  #pragma unroll
  for (int am = 0; am < 4; am++) {
    int nodeLoc = (wr << 6) + (am << 4) + (l4 << 2);      // + j
    float4 dn4 = *(const float4*)(dvB + r0 + nodeLoc);
    float dn[4] = {dn4.x, dn4.y, dn4.z, dn4.w};
    #pragma unroll
    for (int nf = 0; nf < NFO; nf++) {
      int fo = wf * (F_OUT / 4) + (nf << 4) + l15;
      float bb = bias[fo];
      float v[4];
      #pragma unroll
      for (int j = 0; j < 4; j++) v[j] = fmaxf(acc2[am][nf][j] + bb, 0.f);
      if (!FINAL) {
        ushort4 p;
        p.x = (unsigned short)f2bf(v[0] * dn[0]);
        p.y = (unsigned short)f2bf(v[1] * dn[1]);
        p.z = (unsigned short)f2bf(v[2] * dn[2]);
        p.w = (unsigned short)f2bf(v[3] * dn[3]);
        size_t e = (size_t)bw * (F_OUT * 1024) + ((size_t)(fo >> 4) << 14)
                 + ((size_t)((rb << 2) + (wr << 1) + (am >> 1)) << 9)
                 + ((size_t)(((am & 1) << 1) + (l4 >> 1)) << 7)
                 + ((fo & 15) << 3) + ((l4 & 1) << 2);
        *(ushort4*)(Gout + e) = p;
      } else {
        float* ob = Out + ((size_t)(bw << 10) + r0 + nodeLoc) * F_OUT + fo;
        ob[0]         = v[0];
        ob[F_OUT]     = v[1];
        ob[2 * F_OUT] = v[2];
        ob[3 * F_OUT] = v[3];
      }
    }
  }
}

extern "C" void kernel_launch(void* const* d_in, const int* in_sizes, int n_in,
                              void* d_out, int out_size, void* d_ws, size_t ws_size,
                              hipStream_t stream) {
  const float* X   = (const float*)d_in[0];
  const float* adj = (const float*)d_in[1];
  const float* W1  = (const float*)d_in[2];
  const float* b1  = (const float*)d_in[3];
  const float* W2  = (const float*)d_in[4];
  const float* b2  = (const float*)d_in[5];
  const float* W3  = (const float*)d_in[6];
  const float* b3  = (const float*)d_in[7];
  float* out = (float*)d_out;

  char* ws = (char*)d_ws;
  float* dinv = (float*)ws;                              // 128 KB
  short* WT1  = (short*)(ws + 131072);                   // 128 KB
  short* WT2  = (short*)(ws + 262144);                   // 128 KB
  short* WT3  = (short*)(ws + 393216);                   //  64 KB
  short* bufA = (short*)(ws + 458752);                   //  16 MB
  short* bufB = (short*)(ws + 458752 + 16777216);        //  16 MB
  short* Ahat = (short*)(ws + 458752 + 2 * 16777216);    //  64 MB

  dinv_cast<<<2048, 256, 0, stream>>>(adj, dinv, Ahat);
  transpose_x<<<dim3(16, 4, 32), 256, 0, stream>>>(X, dinv, bufA);
  transpose_w<<<256, 256, 0, stream>>>(W1, WT1, 256);
  transpose_w<<<256, 256, 0, stream>>>(W2, WT2, 256);
  transpose_w<<<128, 256, 0, stream>>>(W3, WT3, 128);

  gcn_layer<256, false><<<256, 512, 0, stream>>>(Ahat, dinv, bufA, WT1, b1, bufB, nullptr);
  gcn_layer<256, false><<<256, 512, 0, stream>>>(Ahat, dinv, bufB, WT2, b2, bufA, nullptr);
  gcn_layer<128, true ><<<256, 512, 0, stream>>>(Ahat, dinv, bufA, WT3, b3, nullptr, out);
}

// Round 9
// 140.134 us; speedup vs baseline: 1.0594x; 1.0594x over previous
//
#include <hip/hip_runtime.h>
#include <hip/hip_bf16.h>
#include <cstdint>
#include <cstddef>

#define NN 1024
#define FF 256

typedef __attribute__((ext_vector_type(8))) short bf16x8;
typedef __attribute__((ext_vector_type(4))) float f32x4;

__device__ __forceinline__ short f2bf(float x) {
  unsigned int u = __float_as_uint(x);
  u = (u + 0x7fffu + ((u >> 16) & 1u)) >> 16;   // RNE
  return (short)u;
}

// ---- PT tiled layout (all bf16 matrices) ----
// 16-row x 32-k tiles (512 elems): elem(row,k) = ((k&31)>>3)*128 + (row&15)*8 + (k&7)
// A wave load at (tile_base + lane*8) IS the MFMA fragment:
//   lane -> (row = lane&15, k = (lane>>4)*8 + j)
// Ahat (1024x1024/bw): bw<<20 + (r>>4)<<14 + (k>>5)<<9 + pt(r,k)
// G    (F x 1024/bw) : bw*F*1024 + (f>>4)<<14 + (n>>5)<<9 + pt(f,n)
// WT   (F_OUT x 256) : (fo>>4)*4096 + (fi>>5)<<9 + pt(fo,fi)

// ---- fused: d = rsqrt(rowsum(adj)+1), Ahat = (adj+I) bf16 PT-tiled ---------
__global__ __launch_bounds__(256)
void dinv_cast(const float* __restrict__ adj, float* __restrict__ dinv,
               short* __restrict__ Ahat) {
  __shared__ float wsum[64];
  int b = blockIdx.x;                          // 0..2047 = bw*64 + stripe
  int bw = b >> 6, s = b & 63;
  int t = threadIdx.x;
  int wid = t >> 6, lane = t & 63;
  int row = lane & 15;                         // local row in stripe
  int rloc = (s << 4) + row;                   // row in matrix
  int kg = (lane >> 4) & 3;
  const float* arow = adj + ((size_t)(bw << 10) + rloc) * NN;
  short* outb = Ahat + ((size_t)bw << 20) + ((size_t)s << 14) + (t << 3);
  float ssum = 0.f;
  #pragma unroll
  for (int it = 0; it < 8; it++) {
    int col = (it << 7) + (wid << 5) + (kg << 3);
    float4 a0 = *(const float4*)(arow + col);
    float4 a1 = *(const float4*)(arow + col + 4);
    float v[8] = {a0.x, a0.y, a0.z, a0.w, a1.x, a1.y, a1.z, a1.w};
    union { ushort o[8]; int4 q; } pk;
    #pragma unroll
    for (int j = 0; j < 8; j++) {
      v[j] += (rloc == col + j) ? 1.f : 0.f;
      ssum += v[j];
      pk.o[j] = (ushort)f2bf(v[j]);
    }
    *(int4*)(outb + (it << 11)) = pk.q;
  }
  ssum += __shfl_down(ssum, 32, 64);
  ssum += __shfl_down(ssum, 16, 64);
  if (lane < 16) wsum[(wid << 4) + lane] = ssum;
  __syncthreads();
  if (t < 16) {
    float tot = wsum[t] + wsum[16 + t] + wsum[32 + t] + wsum[48 + t];
    dinv[(bw << 10) + (s << 4) + t] = rsqrtf(tot);
  }
}

// ---- X [bw][n][256] fp32 -> G1 = d[n]*X, PT(f, n) bf16 ---------------------
__global__ __launch_bounds__(256)
void transpose_x(const float* __restrict__ X, const float* __restrict__ dinv,
                 short* __restrict__ XT) {
  __shared__ short T[64][72];
  int bwo = blockIdx.z;
  int n0 = blockIdx.x << 6, f0 = blockIdx.y << 6;
  int t = threadIdx.x;
  {
    int n = t >> 2, fc = (t & 3) << 4;
    float dn = dinv[(bwo << 10) + n0 + n];
    const float* src = X + (((size_t)bwo * NN + n0 + n) * FF) + f0 + fc;
    #pragma unroll
    for (int i = 0; i < 4; i++) {
      float4 v = ((const float4*)src)[i];
      ushort4 p;
      p.x = (unsigned short)f2bf(v.x * dn); p.y = (unsigned short)f2bf(v.y * dn);
      p.z = (unsigned short)f2bf(v.z * dn); p.w = (unsigned short)f2bf(v.w * dn);
      *(ushort4*)&T[n][fc + (i << 2)] = p;
    }
  }
  __syncthreads();
  {
    int f = t >> 2, nc = (t & 3) << 4;
    int fg = f0 + f, ng = n0 + nc;
    short tmp[16];
    #pragma unroll
    for (int i = 0; i < 16; i++) tmp[i] = T[nc + i][f];
    size_t e0 = ((size_t)bwo << 18) + ((size_t)(fg >> 4) << 14) + ((ng >> 5) << 9)
              + (((ng & 31) >> 3) << 7) + ((fg & 15) << 3);
    *(int4*)(XT + e0)       = *(int4*)&tmp[0];
    *(int4*)(XT + e0 + 128) = *(int4*)&tmp[8];
  }
}

// ---- W [256][FO] fp32 -> WT PT(fo, fi) bf16 --------------------------------
__global__ __launch_bounds__(256)
void transpose_w(const float* __restrict__ W, short* __restrict__ WT, int FO) {
  int idx = blockIdx.x * 256 + threadIdx.x;
  if (idx >= FO * 256) return;
  int fo = idx >> 8, fi = idx & 255;
  size_t e = (size_t)((fo >> 4) << 12) + ((fi >> 5) << 9)
           + (((fi & 31) >> 3) << 7) + ((fo & 15) << 3) + (fi & 7);
  WT[e] = f2bf(W[fi * FO + fo]);
}

// ---------------- fused layer ----------------------------------------------
// Grid 256 (8 XCD x 4 bw x 8 rb), 512 thr (8 waves = 2wr x 4wf), 1 block/CU.
// Block tile: 128 r x 256 f; wave 64 r x 64 f. ALL operands register-direct
// (PT coalesced 1KB wave-loads); depth-2 pipeline. BARE s_barrier per K64 as
// wave-convergence hint (no LDS in stage 1 -> no drain needed): keeps the
// x4/x2 fragment duplication L1-resident. One syncthreads at agg spill.
template<int F_OUT, bool FINAL>
__global__ __launch_bounds__(512, 2)
void gcn_layer(const short* __restrict__ Ahat,    // PT tiled (A+I) bf16
               const float* __restrict__ dinv,
               const short* __restrict__ Gin,     // PT tiled g = d*h, F=256
               const short* __restrict__ WT,      // PT tiled
               const float* __restrict__ bias,
               short* __restrict__ Gout,          // PT tiled, F_OUT
               float* __restrict__ Out) {         // [32][1024][F_OUT] fp32
  __shared__ short aggL[128 * 272];               // 128 r x 544B rows

  int b = blockIdx.x;
  int x = b & 7, m = b >> 3;
  int bw = (x << 2) + (m >> 3);                   // same-XCD neighbors share bw
  int rb = m & 7;
  int r0 = rb << 7;                               // 128 rows / block

  int tid = threadIdx.x;
  int wid = tid >> 6, lane = tid & 63;
  int l15 = lane & 15, l4 = lane >> 4;            // l4 in 0..3
  int wr = wid >> 2, wf = wid & 3;

  const short* Hb = Gin  + ((size_t)bw << 18) + ((size_t)(wf << 2) << 14) + (lane << 3);
  const short* Ab = Ahat + ((size_t)bw << 20)
                  + ((size_t)((rb << 3) + (wr << 2)) << 14) + (lane << 3);
  const float* dvB = dinv + (bw << 10);

  f32x4 acc[4][4];                                // [ah(f)][aa(r)]
  #pragma unroll
  for (int ah = 0; ah < 4; ah++)
    #pragma unroll
    for (int aa = 0; aa < 4; aa++) acc[ah][aa] = f32x4{0.f, 0.f, 0.f, 0.f};

  bf16x8 hE[4], aE[4], hO[4], aO[4];

#define LD(HB, AB, T)                                                         \
  {                                                                           \
    _Pragma("unroll")                                                         \
    for (int ah = 0; ah < 4; ah++)                                            \
      HB[ah] = *(const bf16x8*)(Hb + ah * 16384 + (T) * 512);                 \
    _Pragma("unroll")                                                         \
    for (int aa = 0; aa < 4; aa++)                                            \
      AB[aa] = *(const bf16x8*)(Ab + aa * 16384 + (T) * 512);                 \
  }
#define MM(HB, AB)                                                            \
  __builtin_amdgcn_s_setprio(1);                                              \
  _Pragma("unroll")                                                           \
  for (int ah = 0; ah < 4; ah++)                                              \
    _Pragma("unroll")                                                         \
    for (int aa = 0; aa < 4; aa++)                                            \
      acc[ah][aa] = __builtin_amdgcn_mfma_f32_16x16x32_bf16(                  \
          HB[ah], AB[aa], acc[ah][aa], 0, 0, 0);                              \
  __builtin_amdgcn_s_setprio(0);

  LD(hE, aE, 0);
  LD(hO, aO, 1);
  #pragma unroll
  for (int it = 0; it < 16; ++it) {
    __builtin_amdgcn_s_barrier();                // convergence only: no drain
    MM(hE, aE);
    if (it < 15) LD(hE, aE, 2 * it + 2);
    MM(hO, aO);
    if (it < 15) LD(hO, aO, 2 * it + 3);
  }
#undef LD
#undef MM

  // ---- agg = d[r]*acc -> LDS bf16 [128][272], XOR-swizzled ----
  float dsc[4];
  #pragma unroll
  for (int aa = 0; aa < 4; aa++) dsc[aa] = dvB[r0 + (wr << 6) + (aa << 4) + l15];
  #pragma unroll
  for (int ah = 0; ah < 4; ah++)
    #pragma unroll
    for (int aa = 0; aa < 4; aa++) {
      int r = (wr << 6) + (aa << 4) + l15;
      int fB = ((wf << 6) + (ah << 4) + (l4 << 2)) << 1;   // byte col
      int off = (r * 544 + (fB ^ ((r & 7) << 4))) >> 1;
      ushort4 p;
      p.x = (unsigned short)f2bf(acc[ah][aa][0] * dsc[aa]);
      p.y = (unsigned short)f2bf(acc[ah][aa][1] * dsc[aa]);
      p.z = (unsigned short)f2bf(acc[ah][aa][2] * dsc[aa]);
      p.w = (unsigned short)f2bf(acc[ah][aa][3] * dsc[aa]);
      *(ushort4*)(aggL + off) = p;
    }
  __syncthreads();

  // ---- stage 2: out = relu(agg @ W + b), K = 256, W from L2 ----
  constexpr int NFO = F_OUT / 64;                 // fo-tiles per wave
  const short* Wbase = WT + (size_t)(wf * NFO) * 4096 + (lane << 3);
  f32x4 acc2[4][NFO];
  #pragma unroll
  for (int am = 0; am < 4; am++)
    #pragma unroll
    for (int nf = 0; nf < NFO; nf++) acc2[am][nf] = f32x4{0.f, 0.f, 0.f, 0.f};

  #pragma unroll
  for (int kt = 0; kt < 8; kt++) {
    bf16x8 af[4];
    #pragma unroll
    for (int am = 0; am < 4; am++) {
      int r = (wr << 6) + (am << 4) + l15;
      int fB = (kt << 6) + (l4 << 4);
      af[am] = *(const bf16x8*)(aggL + ((r * 544 + (fB ^ ((r & 7) << 4))) >> 1));
    }
    #pragma unroll
    for (int nf = 0; nf < NFO; nf++) {
      bf16x8 wv = *(const bf16x8*)(Wbase + (size_t)nf * 4096 + (kt << 9));
      #pragma unroll
      for (int am = 0; am < 4; am++)
        acc2[am][nf] = __builtin_amdgcn_mfma_f32_16x16x32_bf16(af[am], wv, acc2[am][nf], 0, 0, 0);
    }
  }

  // ---- epilogue: bias + relu (+d[node] for g-form) + store ----
  #pragma unroll
  for (int am = 0; am < 4; am++) {
    int nodeLoc = (wr << 6) + (am << 4) + (l4 << 2);      // + j
    float4 dn4 = *(const float4*)(dvB + r0 + nodeLoc);
    float dn[4] = {dn4.x, dn4.y, dn4.z, dn4.w};
    #pragma unroll
    for (int nf = 0; nf < NFO; nf++) {
      int fo = wf * (F_OUT / 4) + (nf << 4) + l15;
      float bb = bias[fo];
      float v[4];
      #pragma unroll
      for (int j = 0; j < 4; j++) v[j] = fmaxf(acc2[am][nf][j] + bb, 0.f);
      if (!FINAL) {
        ushort4 p;
        p.x = (unsigned short)f2bf(v[0] * dn[0]);
        p.y = (unsigned short)f2bf(v[1] * dn[1]);
        p.z = (unsigned short)f2bf(v[2] * dn[2]);
        p.w = (unsigned short)f2bf(v[3] * dn[3]);
        size_t e = (size_t)bw * (F_OUT * 1024) + ((size_t)(fo >> 4) << 14)
                 + ((size_t)((rb << 2) + (wr << 1) + (am >> 1)) << 9)
                 + ((size_t)(((am & 1) << 1) + (l4 >> 1)) << 7)
                 + ((fo & 15) << 3) + ((l4 & 1) << 2);
        *(ushort4*)(Gout + e) = p;
      } else {
        float* ob = Out + ((size_t)(bw << 10) + r0 + nodeLoc) * F_OUT + fo;
        ob[0]         = v[0];
        ob[F_OUT]     = v[1];
        ob[2 * F_OUT] = v[2];
        ob[3 * F_OUT] = v[3];
      }
    }
  }
}

extern "C" void kernel_launch(void* const* d_in, const int* in_sizes, int n_in,
                              void* d_out, int out_size, void* d_ws, size_t ws_size,
                              hipStream_t stream) {
  const float* X   = (const float*)d_in[0];
  const float* adj = (const float*)d_in[1];
  const float* W1  = (const float*)d_in[2];
  const float* b1  = (const float*)d_in[3];
  const float* W2  = (const float*)d_in[4];
  const float* b2  = (const float*)d_in[5];
  const float* W3  = (const float*)d_in[6];
  const float* b3  = (const float*)d_in[7];
  float* out = (float*)d_out;

  char* ws = (char*)d_ws;
  float* dinv = (float*)ws;                              // 128 KB
  short* WT1  = (short*)(ws + 131072);                   // 128 KB
  short* WT2  = (short*)(ws + 262144);                   // 128 KB
  short* WT3  = (short*)(ws + 393216);                   //  64 KB
  short* bufA = (short*)(ws + 458752);                   //  16 MB
  short* bufB = (short*)(ws + 458752 + 16777216);        //  16 MB
  short* Ahat = (short*)(ws + 458752 + 2 * 16777216);    //  64 MB

  dinv_cast<<<2048, 256, 0, stream>>>(adj, dinv, Ahat);
  transpose_x<<<dim3(16, 4, 32), 256, 0, stream>>>(X, dinv, bufA);
  transpose_w<<<256, 256, 0, stream>>>(W1, WT1, 256);
  transpose_w<<<256, 256, 0, stream>>>(W2, WT2, 256);
  transpose_w<<<128, 256, 0, stream>>>(W3, WT3, 128);

  gcn_layer<256, false><<<256, 512, 0, stream>>>(Ahat, dinv, bufA, WT1, b1, bufB, nullptr);
  gcn_layer<256, false><<<256, 512, 0, stream>>>(Ahat, dinv, bufB, WT2, b2, bufA, nullptr);
  gcn_layer<128, true ><<<256, 512, 0, stream>>>(Ahat, dinv, bufA, WT3, b3, nullptr, out);
}

// Round 10
// 135.305 us; speedup vs baseline: 1.0972x; 1.0357x over previous
//
#include <hip/hip_runtime.h>
#include <hip/hip_bf16.h>
#include <cstdint>
#include <cstddef>

#define NN 1024
#define FF 256

typedef __attribute__((ext_vector_type(8))) short bf16x8;
typedef __attribute__((ext_vector_type(4))) float f32x4;

__device__ __forceinline__ short f2bf(float x) {
  unsigned int u = __float_as_uint(x);
  u = (u + 0x7fffu + ((u >> 16) & 1u)) >> 16;   // RNE
  return (short)u;
}

// ---- PT tiled layout (all bf16 matrices) ----
// 16-row x 32-k tiles (512 elems): elem(row,k) = ((k&31)>>3)*128 + (row&15)*8 + (k&7)
// A wave load at (tile_base + lane*8) IS the MFMA fragment:
//   lane -> (row = lane&15, k = (lane>>4)*8 + j)
// Ahat (1024x1024/bw): bw<<20 + (r>>4)<<14 + (k>>5)<<9 + pt(r,k)
// G    (F x 1024/bw) : bw*F*1024 + (f>>4)<<14 + (n>>5)<<9 + pt(f,n)
// WT   (F_OUT x 256) : (fo>>4)*4096 + (fi>>5)<<9 + pt(fo,fi)

// ---- fused: d = rsqrt(rowsum(adj)+1), Ahat = (adj+I) bf16 PT-tiled ---------
__global__ __launch_bounds__(256)
void dinv_cast(const float* __restrict__ adj, float* __restrict__ dinv,
               short* __restrict__ Ahat) {
  __shared__ float wsum[64];
  int b = blockIdx.x;                          // 0..2047 = bw*64 + stripe
  int bw = b >> 6, s = b & 63;
  int t = threadIdx.x;
  int wid = t >> 6, lane = t & 63;
  int row = lane & 15;                         // local row in stripe
  int rloc = (s << 4) + row;                   // row in matrix
  int kg = (lane >> 4) & 3;
  const float* arow = adj + ((size_t)(bw << 10) + rloc) * NN;
  short* outb = Ahat + ((size_t)bw << 20) + ((size_t)s << 14) + (t << 3);
  float ssum = 0.f;
  #pragma unroll
  for (int it = 0; it < 8; it++) {
    int col = (it << 7) + (wid << 5) + (kg << 3);
    float4 a0 = *(const float4*)(arow + col);
    float4 a1 = *(const float4*)(arow + col + 4);
    float v[8] = {a0.x, a0.y, a0.z, a0.w, a1.x, a1.y, a1.z, a1.w};
    union { ushort o[8]; int4 q; } pk;
    #pragma unroll
    for (int j = 0; j < 8; j++) {
      v[j] += (rloc == col + j) ? 1.f : 0.f;
      ssum += v[j];
      pk.o[j] = (ushort)f2bf(v[j]);
    }
    *(int4*)(outb + (it << 11)) = pk.q;
  }
  ssum += __shfl_down(ssum, 32, 64);
  ssum += __shfl_down(ssum, 16, 64);
  if (lane < 16) wsum[(wid << 4) + lane] = ssum;
  __syncthreads();
  if (t < 16) {
    float tot = wsum[t] + wsum[16 + t] + wsum[32 + t] + wsum[48 + t];
    dinv[(bw << 10) + (s << 4) + t] = rsqrtf(tot);
  }
}

// ---- X [bw][n][256] fp32 -> G1 = d[n]*X, PT(f, n) bf16 ---------------------
__global__ __launch_bounds__(256)
void transpose_x(const float* __restrict__ X, const float* __restrict__ dinv,
                 short* __restrict__ XT) {
  __shared__ short T[64][72];
  int bwo = blockIdx.z;
  int n0 = blockIdx.x << 6, f0 = blockIdx.y << 6;
  int t = threadIdx.x;
  {
    int n = t >> 2, fc = (t & 3) << 4;
    float dn = dinv[(bwo << 10) + n0 + n];
    const float* src = X + (((size_t)bwo * NN + n0 + n) * FF) + f0 + fc;
    #pragma unroll
    for (int i = 0; i < 4; i++) {
      float4 v = ((const float4*)src)[i];
      ushort4 p;
      p.x = (unsigned short)f2bf(v.x * dn); p.y = (unsigned short)f2bf(v.y * dn);
      p.z = (unsigned short)f2bf(v.z * dn); p.w = (unsigned short)f2bf(v.w * dn);
      *(ushort4*)&T[n][fc + (i << 2)] = p;
    }
  }
  __syncthreads();
  {
    int f = t >> 2, nc = (t & 3) << 4;
    int fg = f0 + f, ng = n0 + nc;
    short tmp[16];
    #pragma unroll
    for (int i = 0; i < 16; i++) tmp[i] = T[nc + i][f];
    size_t e0 = ((size_t)bwo << 18) + ((size_t)(fg >> 4) << 14) + ((ng >> 5) << 9)
              + (((ng & 31) >> 3) << 7) + ((fg & 15) << 3);
    *(int4*)(XT + e0)       = *(int4*)&tmp[0];
    *(int4*)(XT + e0 + 128) = *(int4*)&tmp[8];
  }
}

// ---- all three W -> WT PT, one launch --------------------------------------
__global__ __launch_bounds__(256)
void transpose_w3(const float* __restrict__ W1, const float* __restrict__ W2,
                  const float* __restrict__ W3,
                  short* __restrict__ T1, short* __restrict__ T2,
                  short* __restrict__ T3) {
  int idx = blockIdx.x * 256 + threadIdx.x;    // 0..163839
  const float* W; short* T; int FO; int loc;
  if (idx < 65536)       { W = W1; T = T1; FO = 256; loc = idx; }
  else if (idx < 131072) { W = W2; T = T2; FO = 256; loc = idx - 65536; }
  else                   { W = W3; T = T3; FO = 128; loc = idx - 131072; }
  int fo = (FO == 256) ? (loc >> 8) : (loc >> 8);      // loc / 256? careful
  // loc is over FO*256 elements laid out as fo*256 + fi
  fo = loc >> 8; int fi = loc & 255;
  if (fo >= FO) return;
  size_t e = (size_t)((fo >> 4) << 12) + ((fi >> 5) << 9)
           + (((fi & 31) >> 3) << 7) + ((fo & 15) << 3) + (fi & 7);
  T[e] = f2bf(W[fi * FO + fo]);
}

// ---------------- fused layer ----------------------------------------------
// Grid 256 (8 XCD x 4 bw x 8 rb), 512 thr (8 waves = 2wr x 4wf), 1 block/CU.
// Block tile: 128 r x 256 f; wave 64 r x 64 f. ALL operands register-direct
// (PT coalesced 1KB wave-loads); DEPTH-3 named-buffer pipeline (covers L3
// latency on the streamed A operand). No barriers in stage 1.
template<int F_OUT, bool FINAL>
__global__ __launch_bounds__(512, 2)
void gcn_layer(const short* __restrict__ Ahat,    // PT tiled (A+I) bf16
               const float* __restrict__ dinv,
               const short* __restrict__ Gin,     // PT tiled g = d*h, F=256
               const short* __restrict__ WT,      // PT tiled
               const float* __restrict__ bias,
               short* __restrict__ Gout,          // PT tiled, F_OUT
               float* __restrict__ Out) {         // [32][1024][F_OUT] fp32
  __shared__ short aggL[128 * 272];               // 128 r x 544B rows

  int b = blockIdx.x;
  int x = b & 7, m = b >> 3;
  int bw = (x << 2) + (m >> 3);                   // same-XCD neighbors share bw
  int rb = m & 7;
  int r0 = rb << 7;                               // 128 rows / block

  int tid = threadIdx.x;
  int wid = tid >> 6, lane = tid & 63;
  int l15 = lane & 15, l4 = lane >> 4;            // l4 in 0..3
  int wr = wid >> 2, wf = wid & 3;

  const short* Hb = Gin  + ((size_t)bw << 18) + ((size_t)(wf << 2) << 14) + (lane << 3);
  const short* Ab = Ahat + ((size_t)bw << 20)
                  + ((size_t)((rb << 3) + (wr << 2)) << 14) + (lane << 3);
  const float* dvB = dinv + (bw << 10);

  f32x4 acc[4][4];                                // [ah(f)][aa(r)]
  #pragma unroll
  for (int ah = 0; ah < 4; ah++)
    #pragma unroll
    for (int aa = 0; aa < 4; aa++) acc[ah][aa] = f32x4{0.f, 0.f, 0.f, 0.f};

  bf16x8 h0[4], a0[4], h1[4], a1[4], h2[4], a2[4];

#define LD(HB, AB, T)                                                         \
  {                                                                           \
    _Pragma("unroll")                                                         \
    for (int ah = 0; ah < 4; ah++)                                            \
      HB[ah] = *(const bf16x8*)(Hb + ah * 16384 + (T) * 512);                 \
    _Pragma("unroll")                                                         \
    for (int aa = 0; aa < 4; aa++)                                            \
      AB[aa] = *(const bf16x8*)(Ab + aa * 16384 + (T) * 512);                 \
  }
#define MM(HB, AB)                                                            \
  __builtin_amdgcn_s_setprio(1);                                              \
  _Pragma("unroll")                                                           \
  for (int ah = 0; ah < 4; ah++)                                              \
    _Pragma("unroll")                                                         \
    for (int aa = 0; aa < 4; aa++)                                            \
      acc[ah][aa] = __builtin_amdgcn_mfma_f32_16x16x32_bf16(                  \
          HB[ah], AB[aa], acc[ah][aa], 0, 0, 0);                              \
  __builtin_amdgcn_s_setprio(0);

  LD(h0, a0, 0);
  LD(h1, a1, 1);
  LD(h2, a2, 2);
  #pragma unroll
  for (int it = 0; it < 10; ++it) {               // 3 K32-steps per iter = 30
    MM(h0, a0);
    if (3 * it + 3 < 32) LD(h0, a0, 3 * it + 3);
    MM(h1, a1);
    if (3 * it + 4 < 32) LD(h1, a1, 3 * it + 4);
    MM(h2, a2);
    if (3 * it + 5 < 32) LD(h2, a2, 3 * it + 5);
  }
  MM(h0, a0);                                     // step 30
  MM(h1, a1);                                     // step 31
#undef LD
#undef MM

  // ---- agg = d[r]*acc -> LDS bf16 [128][272], XOR-swizzled ----
  float dsc[4];
  #pragma unroll
  for (int aa = 0; aa < 4; aa++) dsc[aa] = dvB[r0 + (wr << 6) + (aa << 4) + l15];
  #pragma unroll
  for (int ah = 0; ah < 4; ah++)
    #pragma unroll
    for (int aa = 0; aa < 4; aa++) {
      int r = (wr << 6) + (aa << 4) + l15;
      int fB = ((wf << 6) + (ah << 4) + (l4 << 2)) << 1;   // byte col
      int off = (r * 544 + (fB ^ ((r & 7) << 4))) >> 1;
      ushort4 p;
      p.x = (unsigned short)f2bf(acc[ah][aa][0] * dsc[aa]);
      p.y = (unsigned short)f2bf(acc[ah][aa][1] * dsc[aa]);
      p.z = (unsigned short)f2bf(acc[ah][aa][2] * dsc[aa]);
      p.w = (unsigned short)f2bf(acc[ah][aa][3] * dsc[aa]);
      *(ushort4*)(aggL + off) = p;
    }
  __syncthreads();

  // ---- stage 2: out = relu(agg @ W + b), K = 256, W from L2 ----
  constexpr int NFO = F_OUT / 64;                 // fo-tiles per wave
  const short* Wbase = WT + (size_t)(wf * NFO) * 4096 + (lane << 3);
  f32x4 acc2[4][NFO];
  #pragma unroll
  for (int am = 0; am < 4; am++)
    #pragma unroll
    for (int nf = 0; nf < NFO; nf++) acc2[am][nf] = f32x4{0.f, 0.f, 0.f, 0.f};

  #pragma unroll
  for (int kt = 0; kt < 8; kt++) {
    bf16x8 af[4];
    #pragma unroll
    for (int am = 0; am < 4; am++) {
      int r = (wr << 6) + (am << 4) + l15;
      int fB = (kt << 6) + (l4 << 4);
      af[am] = *(const bf16x8*)(aggL + ((r * 544 + (fB ^ ((r & 7) << 4))) >> 1));
    }
    #pragma unroll
    for (int nf = 0; nf < NFO; nf++) {
      bf16x8 wv = *(const bf16x8*)(Wbase + (size_t)nf * 4096 + (kt << 9));
      #pragma unroll
      for (int am = 0; am < 4; am++)
        acc2[am][nf] = __builtin_amdgcn_mfma_f32_16x16x32_bf16(af[am], wv, acc2[am][nf], 0, 0, 0);
    }
  }

  // ---- epilogue: bias + relu (+d[node] for g-form) + store ----
  #pragma unroll
  for (int am = 0; am < 4; am++) {
    int nodeLoc = (wr << 6) + (am << 4) + (l4 << 2);      // + j
    float4 dn4 = *(const float4*)(dvB + r0 + nodeLoc);
    float dn[4] = {dn4.x, dn4.y, dn4.z, dn4.w};
    #pragma unroll
    for (int nf = 0; nf < NFO; nf++) {
      int fo = wf * (F_OUT / 4) + (nf << 4) + l15;
      float bb = bias[fo];
      float v[4];
      #pragma unroll
      for (int j = 0; j < 4; j++) v[j] = fmaxf(acc2[am][nf][j] + bb, 0.f);
      if (!FINAL) {
        ushort4 p;
        p.x = (unsigned short)f2bf(v[0] * dn[0]);
        p.y = (unsigned short)f2bf(v[1] * dn[1]);
        p.z = (unsigned short)f2bf(v[2] * dn[2]);
        p.w = (unsigned short)f2bf(v[3] * dn[3]);
        size_t e = (size_t)bw * (F_OUT * 1024) + ((size_t)(fo >> 4) << 14)
                 + ((size_t)((rb << 2) + (wr << 1) + (am >> 1)) << 9)
                 + ((size_t)(((am & 1) << 1) + (l4 >> 1)) << 7)
                 + ((fo & 15) << 3) + ((l4 & 1) << 2);
        *(ushort4*)(Gout + e) = p;
      } else {
        float* ob = Out + ((size_t)(bw << 10) + r0 + nodeLoc) * F_OUT + fo;
        ob[0]         = v[0];
        ob[F_OUT]     = v[1];
        ob[2 * F_OUT] = v[2];
        ob[3 * F_OUT] = v[3];
      }
    }
  }
}

extern "C" void kernel_launch(void* const* d_in, const int* in_sizes, int n_in,
                              void* d_out, int out_size, void* d_ws, size_t ws_size,
                              hipStream_t stream) {
  const float* X   = (const float*)d_in[0];
  const float* adj = (const float*)d_in[1];
  const float* W1  = (const float*)d_in[2];
  const float* b1  = (const float*)d_in[3];
  const float* W2  = (const float*)d_in[4];
  const float* b2  = (const float*)d_in[5];
  const float* W3  = (const float*)d_in[6];
  const float* b3  = (const float*)d_in[7];
  float* out = (float*)d_out;

  char* ws = (char*)d_ws;
  float* dinv = (float*)ws;                              // 128 KB
  short* WT1  = (short*)(ws + 131072);                   // 128 KB
  short* WT2  = (short*)(ws + 262144);                   // 128 KB
  short* WT3  = (short*)(ws + 393216);                   //  64 KB
  short* bufA = (short*)(ws + 458752);                   //  16 MB
  short* bufB = (short*)(ws + 458752 + 16777216);        //  16 MB
  short* Ahat = (short*)(ws + 458752 + 2 * 16777216);    //  64 MB

  dinv_cast<<<2048, 256, 0, stream>>>(adj, dinv, Ahat);
  transpose_w3<<<640, 256, 0, stream>>>(W1, W2, W3, WT1, WT2, WT3);
  transpose_x<<<dim3(16, 4, 32), 256, 0, stream>>>(X, dinv, bufA);

  gcn_layer<256, false><<<256, 512, 0, stream>>>(Ahat, dinv, bufA, WT1, b1, bufB, nullptr);
  gcn_layer<256, false><<<256, 512, 0, stream>>>(Ahat, dinv, bufB, WT2, b2, bufA, nullptr);
  gcn_layer<128, true ><<<256, 512, 0, stream>>>(Ahat, dinv, bufA, WT3, b3, nullptr, out);
}

// Round 11
// 133.409 us; speedup vs baseline: 1.1128x; 1.0142x over previous
//
#include <hip/hip_runtime.h>
#include <hip/hip_bf16.h>
#include <cstdint>
#include <cstddef>

#define NN 1024
#define FF 256

typedef __attribute__((ext_vector_type(8))) short bf16x8;
typedef __attribute__((ext_vector_type(4))) float f32x4;

typedef __attribute__((address_space(1))) const void* gas_ptr;
typedef __attribute__((address_space(3))) void* las_ptr;

__device__ __forceinline__ short f2bf(float x) {
  unsigned int u = __float_as_uint(x);
  u = (u + 0x7fffu + ((u >> 16) & 1u)) >> 16;   // RNE
  return (short)u;
}

// ---- PT tiled layout (all bf16 matrices) ----
// 16-row x 32-k tiles (512 elems): elem(row,k) = ((k&31)>>3)*128 + (row&15)*8 + (k&7)
// A wave load at (tile_base + lane*8) IS the MFMA fragment:
//   lane -> (row = lane&15, k = (lane>>4)*8 + j)
// Ahat (1024x1024/bw): bw<<20 + (r>>4)<<14 + (k>>5)<<9 + pt(r,k)
// G    (F x 1024/bw) : bw*F*1024 + (f>>4)<<14 + (n>>5)<<9 + pt(f,n)
// WT   (F_OUT x 256) : (fo>>4)*4096 + (fi>>5)<<9 + pt(fo,fi)

// ---- fused: d = rsqrt(rowsum(adj)+1), Ahat = (adj+I) bf16 PT-tiled ---------
__global__ __launch_bounds__(256)
void dinv_cast(const float* __restrict__ adj, float* __restrict__ dinv,
               short* __restrict__ Ahat) {
  __shared__ float wsum[64];
  int b = blockIdx.x;                          // 0..2047 = bw*64 + stripe
  int bw = b >> 6, s = b & 63;
  int t = threadIdx.x;
  int wid = t >> 6, lane = t & 63;
  int row = lane & 15;                         // local row in stripe
  int rloc = (s << 4) + row;                   // row in matrix
  int kg = (lane >> 4) & 3;
  const float* arow = adj + ((size_t)(bw << 10) + rloc) * NN;
  short* outb = Ahat + ((size_t)bw << 20) + ((size_t)s << 14) + (t << 3);
  float ssum = 0.f;
  #pragma unroll
  for (int it = 0; it < 8; it++) {
    int col = (it << 7) + (wid << 5) + (kg << 3);
    float4 a0 = *(const float4*)(arow + col);
    float4 a1 = *(const float4*)(arow + col + 4);
    float v[8] = {a0.x, a0.y, a0.z, a0.w, a1.x, a1.y, a1.z, a1.w};
    union { ushort o[8]; int4 q; } pk;
    #pragma unroll
    for (int j = 0; j < 8; j++) {
      v[j] += (rloc == col + j) ? 1.f : 0.f;
      ssum += v[j];
      pk.o[j] = (ushort)f2bf(v[j]);
    }
    *(int4*)(outb + (it << 11)) = pk.q;
  }
  ssum += __shfl_down(ssum, 32, 64);
  ssum += __shfl_down(ssum, 16, 64);
  if (lane < 16) wsum[(wid << 4) + lane] = ssum;
  __syncthreads();
  if (t < 16) {
    float tot = wsum[t] + wsum[16 + t] + wsum[32 + t] + wsum[48 + t];
    dinv[(bw << 10) + (s << 4) + t] = rsqrtf(tot);
  }
}

// ---- X [bw][n][256] fp32 -> G1 = d[n]*X, PT(f, n) bf16 ---------------------
__global__ __launch_bounds__(256)
void transpose_x(const float* __restrict__ X, const float* __restrict__ dinv,
                 short* __restrict__ XT) {
  __shared__ short T[64][72];
  int bwo = blockIdx.z;
  int n0 = blockIdx.x << 6, f0 = blockIdx.y << 6;
  int t = threadIdx.x;
  {
    int n = t >> 2, fc = (t & 3) << 4;
    float dn = dinv[(bwo << 10) + n0 + n];
    const float* src = X + (((size_t)bwo * NN + n0 + n) * FF) + f0 + fc;
    #pragma unroll
    for (int i = 0; i < 4; i++) {
      float4 v = ((const float4*)src)[i];
      ushort4 p;
      p.x = (unsigned short)f2bf(v.x * dn); p.y = (unsigned short)f2bf(v.y * dn);
      p.z = (unsigned short)f2bf(v.z * dn); p.w = (unsigned short)f2bf(v.w * dn);
      *(ushort4*)&T[n][fc + (i << 2)] = p;
    }
  }
  __syncthreads();
  {
    int f = t >> 2, nc = (t & 3) << 4;
    int fg = f0 + f, ng = n0 + nc;
    short tmp[16];
    #pragma unroll
    for (int i = 0; i < 16; i++) tmp[i] = T[nc + i][f];
    size_t e0 = ((size_t)bwo << 18) + ((size_t)(fg >> 4) << 14) + ((ng >> 5) << 9)
              + (((ng & 31) >> 3) << 7) + ((fg & 15) << 3);
    *(int4*)(XT + e0)       = *(int4*)&tmp[0];
    *(int4*)(XT + e0 + 128) = *(int4*)&tmp[8];
  }
}

// ---- all three W -> WT PT, one launch --------------------------------------
__global__ __launch_bounds__(256)
void transpose_w3(const float* __restrict__ W1, const float* __restrict__ W2,
                  const float* __restrict__ W3,
                  short* __restrict__ T1, short* __restrict__ T2,
                  short* __restrict__ T3) {
  int idx = blockIdx.x * 256 + threadIdx.x;    // 0..163839
  const float* W; short* T; int FO; int loc;
  if (idx < 65536)       { W = W1; T = T1; FO = 256; loc = idx; }
  else if (idx < 131072) { W = W2; T = T2; FO = 256; loc = idx - 65536; }
  else                   { W = W3; T = T3; FO = 128; loc = idx - 131072; }
  int fo = loc >> 8, fi = loc & 255;
  if (fo >= FO) return;
  size_t e = (size_t)((fo >> 4) << 12) + ((fi >> 5) << 9)
           + (((fi & 31) >> 3) << 7) + ((fo & 15) << 3) + (fi & 7);
  T[e] = f2bf(W[fi * FO + fo]);
}

// ---------------- fused layer ----------------------------------------------
// Grid 256 (8 XCD x 4 bw x 8 rb), 512 thr (8 waves = 2wr x 4wf), 1 block/CU.
// Block tile: 128 r x 256 f; wave 64 r x 64 f. BOTH operands LDS-staged per
// K64 step (48 KB: A 16 + H 32, PT-linear, conflict-free ds_read), double-
// buffered; ONE vmcnt(0)+s_barrier per step; stage(t+1) issued at body top so
// HBM/L3 latency hides under ds_read+MFMA(t). Kills the x4 A / x2 H L2 dup.
template<int F_OUT, bool FINAL>
__global__ __launch_bounds__(512)
void gcn_layer(const short* __restrict__ Ahat,    // PT tiled (A+I) bf16
               const float* __restrict__ dinv,
               const short* __restrict__ Gin,     // PT tiled g = d*h, F=256
               const short* __restrict__ WT,      // PT tiled
               const float* __restrict__ bias,
               short* __restrict__ Gout,          // PT tiled, F_OUT
               float* __restrict__ Out) {         // [32][1024][F_OUT] fp32
  __shared__ __align__(16) short lds[49152];      // 2 x (A 16KB + H 32KB); aggL reuses

  int b = blockIdx.x;
  int x = b & 7, m = b >> 3;
  int bw = (x << 2) + (m >> 3);                   // same-XCD neighbors share bw
  int rb = m & 7;
  int r0 = rb << 7;                               // 128 rows / block

  int tid = threadIdx.x;
  int wid = tid >> 6, lane = tid & 63;
  int l15 = lane & 15, l4 = lane >> 4;            // l4 in 0..3
  int wr = wid >> 2, wf = wid & 3;

  const float* dvB = dinv + (bw << 10);
  const short* Abase = Ahat + ((size_t)bw << 20) + ((size_t)(rb << 3) << 14);
  const short* Hbase = Gin  + ((size_t)bw << 18);

  // stage K64 tile t into buffer sel: A chunks 0..15 (1KB each), H chunks 0..31
  auto stage = [&](int sel, int t) {
    char* base = (char*)lds + sel * 49152;
    int kb = t << 1;
    #pragma unroll
    for (int i = 0; i < 2; i++) {                 // A: 16 KB
      int slot = (i << 9) + tid;                  // 0..1023
      int c = slot >> 6, o = slot & 63;           // chunk, 16B unit
      const short* g = Abase + ((size_t)(c >> 1) << 14) + ((size_t)(kb + (c & 1)) << 9) + (o << 3);
      __builtin_amdgcn_global_load_lds((gas_ptr)g, (las_ptr)(base + (slot << 4)), 16, 0, 0);
    }
    #pragma unroll
    for (int i = 0; i < 4; i++) {                 // H: 32 KB
      int slot = (i << 9) + tid;                  // 0..2047
      int c = slot >> 6, o = slot & 63;
      const short* g = Hbase + ((size_t)(c >> 1) << 14) + ((size_t)(kb + (c & 1)) << 9) + (o << 3);
      __builtin_amdgcn_global_load_lds((gas_ptr)g, (las_ptr)(base + 16384 + (slot << 4)), 16, 0, 0);
    }
  };

  f32x4 acc[4][4];                                // [ah(f)][aa(r)]
  #pragma unroll
  for (int ah = 0; ah < 4; ah++)
    #pragma unroll
    for (int aa = 0; aa < 4; aa++) acc[ah][aa] = f32x4{0.f, 0.f, 0.f, 0.f};

  stage(0, 0);
  asm volatile("s_waitcnt vmcnt(0)" ::: "memory");
  __builtin_amdgcn_s_barrier();

  for (int t = 0; t < 16; ++t) {
    if (t < 15) stage((t + 1) & 1, t + 1);        // in flight across this body
    const char* base = (const char*)lds + (t & 1) * 49152;
    bf16x8 a[4][2], h[4][2];
    #pragma unroll
    for (int aa = 0; aa < 4; aa++) {
      int c = ((wr << 2) + aa) << 1;
      a[aa][0] = *(const bf16x8*)(base + (c << 10) + (lane << 4));
      a[aa][1] = *(const bf16x8*)(base + ((c + 1) << 10) + (lane << 4));
    }
    #pragma unroll
    for (int ah = 0; ah < 4; ah++) {
      int c = ((wf << 2) + ah) << 1;
      h[ah][0] = *(const bf16x8*)(base + 16384 + (c << 10) + (lane << 4));
      h[ah][1] = *(const bf16x8*)(base + 16384 + ((c + 1) << 10) + (lane << 4));
    }
    __builtin_amdgcn_s_setprio(1);
    #pragma unroll
    for (int kt = 0; kt < 2; kt++)
      #pragma unroll
      for (int ah = 0; ah < 4; ah++)
        #pragma unroll
        for (int aa = 0; aa < 4; aa++)
          acc[ah][aa] = __builtin_amdgcn_mfma_f32_16x16x32_bf16(
              h[ah][kt], a[aa][kt], acc[ah][aa], 0, 0, 0);
    __builtin_amdgcn_s_setprio(0);
    asm volatile("s_waitcnt vmcnt(0)" ::: "memory");   // stage(t+1) landed
    __builtin_amdgcn_sched_barrier(0);
    __builtin_amdgcn_s_barrier();                      // buf(t+1) ready for all
  }

  // ---- agg = d[r]*acc -> LDS bf16 [128][272], XOR-swizzled (reuses bufs) ----
  short* aggL = lds;
  float dsc[4];
  #pragma unroll
  for (int aa = 0; aa < 4; aa++) dsc[aa] = dvB[r0 + (wr << 6) + (aa << 4) + l15];
  #pragma unroll
  for (int ah = 0; ah < 4; ah++)
    #pragma unroll
    for (int aa = 0; aa < 4; aa++) {
      int r = (wr << 6) + (aa << 4) + l15;
      int fB = ((wf << 6) + (ah << 4) + (l4 << 2)) << 1;   // byte col
      int off = (r * 544 + (fB ^ ((r & 7) << 4))) >> 1;
      ushort4 p;
      p.x = (unsigned short)f2bf(acc[ah][aa][0] * dsc[aa]);
      p.y = (unsigned short)f2bf(acc[ah][aa][1] * dsc[aa]);
      p.z = (unsigned short)f2bf(acc[ah][aa][2] * dsc[aa]);
      p.w = (unsigned short)f2bf(acc[ah][aa][3] * dsc[aa]);
      *(ushort4*)(aggL + off) = p;
    }
  __syncthreads();

  // ---- stage 2: out = relu(agg @ W + b), K = 256, W from L2 ----
  constexpr int NFO = F_OUT / 64;                 // fo-tiles per wave
  const short* Wbase = WT + (size_t)(wf * NFO) * 4096 + (lane << 3);
  f32x4 acc2[4][NFO];
  #pragma unroll
  for (int am = 0; am < 4; am++)
    #pragma unroll
    for (int nf = 0; nf < NFO; nf++) acc2[am][nf] = f32x4{0.f, 0.f, 0.f, 0.f};

  #pragma unroll
  for (int kt = 0; kt < 8; kt++) {
    bf16x8 af[4];
    #pragma unroll
    for (int am = 0; am < 4; am++) {
      int r = (wr << 6) + (am << 4) + l15;
      int fB = (kt << 6) + (l4 << 4);
      af[am] = *(const bf16x8*)(aggL + ((r * 544 + (fB ^ ((r & 7) << 4))) >> 1));
    }
    #pragma unroll
    for (int nf = 0; nf < NFO; nf++) {
      bf16x8 wv = *(const bf16x8*)(Wbase + (size_t)nf * 4096 + (kt << 9));
      #pragma unroll
      for (int am = 0; am < 4; am++)
        acc2[am][nf] = __builtin_amdgcn_mfma_f32_16x16x32_bf16(af[am], wv, acc2[am][nf], 0, 0, 0);
    }
  }

  // ---- epilogue: bias + relu (+d[node] for g-form) + store ----
  #pragma unroll
  for (int am = 0; am < 4; am++) {
    int nodeLoc = (wr << 6) + (am << 4) + (l4 << 2);      // + j
    float4 dn4 = *(const float4*)(dvB + r0 + nodeLoc);
    float dn[4] = {dn4.x, dn4.y, dn4.z, dn4.w};
    #pragma unroll
    for (int nf = 0; nf < NFO; nf++) {
      int fo = wf * (F_OUT / 4) + (nf << 4) + l15;
      float bb = bias[fo];
      float v[4];
      #pragma unroll
      for (int j = 0; j < 4; j++) v[j] = fmaxf(acc2[am][nf][j] + bb, 0.f);
      if (!FINAL) {
        ushort4 p;
        p.x = (unsigned short)f2bf(v[0] * dn[0]);
        p.y = (unsigned short)f2bf(v[1] * dn[1]);
        p.z = (unsigned short)f2bf(v[2] * dn[2]);
        p.w = (unsigned short)f2bf(v[3] * dn[3]);
        size_t e = (size_t)bw * (F_OUT * 1024) + ((size_t)(fo >> 4) << 14)
                 + ((size_t)((rb << 2) + (wr << 1) + (am >> 1)) << 9)
                 + ((size_t)(((am & 1) << 1) + (l4 >> 1)) << 7)
                 + ((fo & 15) << 3) + ((l4 & 1) << 2);
        *(ushort4*)(Gout + e) = p;
      } else {
        float* ob = Out + ((size_t)(bw << 10) + r0 + nodeLoc) * F_OUT + fo;
        ob[0]         = v[0];
        ob[F_OUT]     = v[1];
        ob[2 * F_OUT] = v[2];
        ob[3 * F_OUT] = v[3];
      }
    }
  }
}

extern "C" void kernel_launch(void* const* d_in, const int* in_sizes, int n_in,
                              void* d_out, int out_size, void* d_ws, size_t ws_size,
                              hipStream_t stream) {
  const float* X   = (const float*)d_in[0];
  const float* adj = (const float*)d_in[1];
  const float* W1  = (const float*)d_in[2];
  const float* b1  = (const float*)d_in[3];
  const float* W2  = (const float*)d_in[4];
  const float* b2  = (const float*)d_in[5];
  const float* W3  = (const float*)d_in[6];
  const float* b3  = (const float*)d_in[7];
  float* out = (float*)d_out;

  char* ws = (char*)d_ws;
  float* dinv = (float*)ws;                              // 128 KB
  short* WT1  = (short*)(ws + 131072);                   // 128 KB
  short* WT2  = (short*)(ws + 262144);                   // 128 KB
  short* WT3  = (short*)(ws + 393216);                   //  64 KB
  short* bufA = (short*)(ws + 458752);                   //  16 MB
  short* bufB = (short*)(ws + 458752 + 16777216);        //  16 MB
  short* Ahat = (short*)(ws + 458752 + 2 * 16777216);    //  64 MB

  dinv_cast<<<2048, 256, 0, stream>>>(adj, dinv, Ahat);
  transpose_w3<<<640, 256, 0, stream>>>(W1, W2, W3, WT1, WT2, WT3);
  transpose_x<<<dim3(16, 4, 32), 256, 0, stream>>>(X, dinv, bufA);

  gcn_layer<256, false><<<256, 512, 0, stream>>>(Ahat, dinv, bufA, WT1, b1, bufB, nullptr);
  gcn_layer<256, false><<<256, 512, 0, stream>>>(Ahat, dinv, bufB, WT2, b2, bufA, nullptr);
  gcn_layer<128, true ><<<256, 512, 0, stream>>>(Ahat, dinv, bufA, WT3, b3, nullptr, out);
}